// Round 1
// baseline (579.558 us; speedup 1.0000x reference)
//
#include <hip/hip_runtime.h>

// Problem constants (B=2, S=2048, D_IN=2048, H=16, G=4, HD=128)
#define S_LEN 2048
#define NROWS 4096      // B*S
#define DIN   2048
#define DQKV  5120      // 4096 (q|gate) + 512 K + 512 V
#define DQG   4096

typedef __bf16 bf16x8 __attribute__((ext_vector_type(8)));
typedef float  floatx4 __attribute__((ext_vector_type(4)));
typedef unsigned short u16;

#define QK_SCALE 0.08838834764831845f   // 128^-0.5, folded into Q

__device__ __forceinline__ u16 f2bf(float f) {
  unsigned int u = __float_as_uint(f);
  u += 0x7fffu + ((u >> 16) & 1u);   // RNE
  return (u16)(u >> 16);
}
__device__ __forceinline__ float bf2f(u16 v) {
  return __uint_as_float(((unsigned int)v) << 16);
}
// XOR-8 chunk swizzle within each 64-element column group, keyed by row&7.
// Applied to all bf16 GEMM-operand matrices (baked into global layout so the
// position-preserving global_load_lds DMA lands it pre-swizzled in LDS).
__device__ __forceinline__ int swz(int col, int row) {
  return (col & ~63) | ((((col >> 3) & 7) ^ (row & 7)) << 3) | (col & 7);
}

__device__ __forceinline__ void gload_lds16(const void* g, void* l) {
  __builtin_amdgcn_global_load_lds(
      (__attribute__((address_space(1))) void*)(void*)(g),
      (__attribute__((address_space(3))) void*)(l), 16, 0, 0);
}

// ---------------- x fp32 -> bf16, swizzled (C = 2048) ----------------
__global__ __launch_bounds__(256) void cvt_x(const float* __restrict__ src,
                                             u16* __restrict__ dst) {
  const int i = blockIdx.x * 256 + threadIdx.x;   // one float4 per thread
  const int row = i >> 9, col = (i & 511) << 2;   // 512 float4 per row
  const float4 v = reinterpret_cast<const float4*>(src)[i];
  ushort4 o;
  o.x = f2bf(v.x); o.y = f2bf(v.y); o.z = f2bf(v.z); o.w = f2bf(v.w);
  *reinterpret_cast<ushort4*>(dst + (size_t)row * DIN + swz(col, row)) = o;
}

// ---------------- transpose + convert + swizzle: src[R][C] f32 -> dst[C][R] bf16 ----------------
__global__ __launch_bounds__(256) void tcvt(const float* __restrict__ src,
                                            u16* __restrict__ dst,
                                            int R, int C, int dld) {
  __shared__ float tile[32][33];
  const int c0 = blockIdx.x * 32, r0 = blockIdx.y * 32;
  const int t = threadIdx.x;
  {
    const int rl = t >> 3, cl4 = (t & 7) * 4;
    const float4 v = *reinterpret_cast<const float4*>(src + (size_t)(r0 + rl) * C + c0 + cl4);
    tile[rl][cl4 + 0] = v.x; tile[rl][cl4 + 1] = v.y;
    tile[rl][cl4 + 2] = v.z; tile[rl][cl4 + 3] = v.w;
  }
  __syncthreads();
  {
    const int cl = t >> 3, rl4 = (t & 7) * 4;
    ushort4 o;
    o.x = f2bf(tile[rl4 + 0][cl]); o.y = f2bf(tile[rl4 + 1][cl]);
    o.z = f2bf(tile[rl4 + 2][cl]); o.w = f2bf(tile[rl4 + 3][cl]);
    const int rd = c0 + cl, cd = r0 + rl4;      // dst (row, col)
    *reinterpret_cast<ushort4*>(dst + (size_t)rd * dld + swz(cd, rd)) = o;
  }
}

// ---------------- bf16 GEMM, BK=64: C[M][N] = A[M][K] @ Bt[N][K]^T ----------------
// A, Bt stored with swz() layout. C plain (fp32 or bf16).  (kept for the Wo GEMM)
template <bool BF16_OUT>
__global__ __launch_bounds__(256) void gemm_bt(const u16* __restrict__ A,
                                               const u16* __restrict__ Bt,
                                               void* __restrict__ Cv,
                                               int M, int N, int K) {
  __shared__ __align__(16) u16 As[128 * 64];
  __shared__ __align__(16) u16 Bs[128 * 64];
  const int tid = threadIdx.x, wv = tid >> 6, lane = tid & 63;
  const int m0 = blockIdx.y * 128, n0 = blockIdx.x * 128;
  const int wm = (wv >> 1) * 64, wn = (wv & 1) * 64;
  const int frow = lane & 15, quad = lane >> 4, fsw = frow & 7;
  const int srow = lane >> 3, scol = (lane & 7) * 8;
  floatx4 acc[4][4] = {};
  for (int k0 = 0; k0 < K; k0 += 64) {
#pragma unroll
    for (int i = 0; i < 4; ++i) {
      const int rr = (wv * 4 + i) * 8;
      gload_lds16(A  + (size_t)(m0 + rr + srow) * K + k0 + scol, &As[rr * 64]);
      gload_lds16(Bt + (size_t)(n0 + rr + srow) * K + k0 + scol, &Bs[rr * 64]);
    }
    __syncthreads();
#pragma unroll
    for (int ks = 0; ks < 2; ++ks) {
      bf16x8 af[4], bfr[4];
#pragma unroll
      for (int mi = 0; mi < 4; ++mi)
        af[mi] = *reinterpret_cast<const bf16x8*>(
            &As[(wm + mi * 16 + frow) * 64 + (((ks * 4 + quad) ^ fsw) << 3)]);
#pragma unroll
      for (int ni = 0; ni < 4; ++ni)
        bfr[ni] = *reinterpret_cast<const bf16x8*>(
            &Bs[(wn + ni * 16 + frow) * 64 + (((ks * 4 + quad) ^ fsw) << 3)]);
#pragma unroll
      for (int mi = 0; mi < 4; ++mi)
#pragma unroll
        for (int ni = 0; ni < 4; ++ni)
          acc[mi][ni] = __builtin_amdgcn_mfma_f32_16x16x32_bf16(af[mi], bfr[ni], acc[mi][ni], 0, 0, 0);
    }
    __syncthreads();
  }
  const int crow = (lane >> 4) * 4, ccol = lane & 15;
#pragma unroll
  for (int mi = 0; mi < 4; ++mi)
#pragma unroll
    for (int ni = 0; ni < 4; ++ni) {
      const size_t base = (size_t)(m0 + wm + mi * 16 + crow) * N + (n0 + wn + ni * 16 + ccol);
      if constexpr (BF16_OUT) {
        u16* C = (u16*)Cv;
#pragma unroll
        for (int r = 0; r < 4; ++r) C[base + (size_t)r * N] = f2bf(acc[mi][ni][r]);
      } else {
        float* C = (float*)Cv;
#pragma unroll
        for (int r = 0; r < 4; ++r) C[base + (size_t)r * N] = acc[mi][ni][r];
      }
    }
}

// ---------------- 8-phase deep-pipelined bf16 GEMM, 256x320 tile, BK=64 ----------------
// C[M][N] = A[M][K] @ Bt[N][K]^T ; A,Bt swz()-swizzled; C plain bf16.
// 512 threads = 8 waves (2M x 4N), wave tile 128x80 (8x5 16x16 frags).
// LDS: 2 slots x (A 256x64 + B 320x64) = 144 KiB -> 1 WG/CU, 2 waves/SIMD.
// Stage units = 64 rows x 64 k (8 KiB = 1 global_load_lds_dwordx4/thread).
// Phase order per K-tile: (F0,k0),(F1,k0),(F0,k1),(F1,k1) -> B frags reg-reused
// across phase pairs. Stage placement from deadness: A-F0 rows die at end-ph3,
// A-F1 + B at end-ph4 (resp. ph7/ph8 for slot1). Counted vmcnt(2) at ph4/ph8 only.
__global__ __launch_bounds__(512, 2) void gemm_qkv(const u16* __restrict__ A,
                                                   const u16* __restrict__ Bt,
                                                   u16* __restrict__ C,
                                                   int M, int N, int K) {
  __shared__ __align__(16) u16 As[2][256 * 64];   // 64 KiB
  __shared__ __align__(16) u16 Bs[2][320 * 64];   // 80 KiB
  const int tid = threadIdx.x, wv = tid >> 6, lane = tid & 63;
  // XCD-bijective swizzle (grid = 256 WGs, multiple of 8)
  const int nx = gridDim.x;
  const int orig = blockIdx.y * nx + blockIdx.x;
  const int cpx = (nx * gridDim.y) >> 3;
  const int wgid = (orig & 7) * cpx + (orig >> 3);
  const int m0 = (wgid / nx) * 256, n0 = (wgid % nx) * 320;
  const int wm = (wv >> 2) * 128, wn = (wv & 3) * 80;
  const int f = lane & 15, quad = lane >> 4, fs = f & 7;

  const u16* Ab = A  + (size_t)(m0 + wv * 8 + (lane >> 3)) * K + (lane & 7) * 8;
  const u16* Bb = Bt + (size_t)(n0 + wv * 8 + (lane >> 3)) * K + (lane & 7) * 8;

  floatx4 acc[8][5] = {};
  bf16x8 af[4], bfr[5];

  auto stageA = [&](int sl, int t, int u) {
    gload_lds16(Ab + (size_t)u * 64 * K + (size_t)t * 64, &As[sl][(u * 64 + wv * 8) * 64]);
  };
  auto stageB = [&](int sl, int t, int u) {
    gload_lds16(Bb + (size_t)u * 64 * K + (size_t)t * 64, &Bs[sl][(u * 64 + wv * 8) * 64]);
  };
  auto loadA = [&](int sl, int fh, int ks) {
#pragma unroll
    for (int mf = 0; mf < 4; ++mf)
      af[mf] = *reinterpret_cast<const bf16x8*>(
          &As[sl][(wm + fh * 64 + mf * 16 + f) * 64 + ((((ks << 2) + quad) ^ fs) << 3)]);
  };
  auto loadB = [&](int sl, int ks) {
#pragma unroll
    for (int nf = 0; nf < 5; ++nf)
      bfr[nf] = *reinterpret_cast<const bf16x8*>(
          &Bs[sl][(wn + nf * 16 + f) * 64 + ((((ks << 2) + quad) ^ fs) << 3)]);
  };
  auto mmas = [&](int fh) {
#pragma unroll
    for (int mf = 0; mf < 4; ++mf)
#pragma unroll
      for (int nf = 0; nf < 5; ++nf)
        acc[fh * 4 + mf][nf] = __builtin_amdgcn_mfma_f32_16x16x32_bf16(
            af[mf], bfr[nf], acc[fh * 4 + mf][nf], 0, 0, 0);
  };

  // prologue: tile0 -> slot0 (9 units), then tile1 A0,A2 -> slot1 (stay in flight)
#pragma unroll
  for (int u = 0; u < 4; ++u) stageA(0, 0, u);
#pragma unroll
  for (int u = 0; u < 5; ++u) stageB(0, 0, u);
  stageA(1, 1, 0); stageA(1, 1, 2);
  asm volatile("s_waitcnt vmcnt(2)" ::: "memory");
  __builtin_amdgcn_s_barrier();

  const int IT = K >> 7;   // 2 K-tiles per iteration
#pragma unroll 1
  for (int i = 0; i < IT; ++i) {
    const int t0 = 2 * i;
    const bool st = (i < IT - 1);
    // ph1: slot0 (F0,k0); stage A1,A3,B0 of tile t0+1 -> slot1 (dead since end-ph8 prev)
    loadA(0, 0, 0); loadB(0, 0);
    stageA(1, t0 + 1, 1); stageA(1, t0 + 1, 3); stageB(1, t0 + 1, 0);
    __builtin_amdgcn_s_barrier();
    asm volatile("s_waitcnt lgkmcnt(0)" ::: "memory");
    __builtin_amdgcn_s_setprio(1); mmas(0); __builtin_amdgcn_s_setprio(0);
    __builtin_amdgcn_s_barrier();
    // ph2: slot0 (F1,k0); B(k0) frags reused from ph1; stage B1-4 (t0+1)
    loadA(0, 1, 0);
    stageB(1, t0 + 1, 1); stageB(1, t0 + 1, 2); stageB(1, t0 + 1, 3); stageB(1, t0 + 1, 4);
    __builtin_amdgcn_s_barrier();
    asm volatile("s_waitcnt lgkmcnt(0)" ::: "memory");
    __builtin_amdgcn_s_setprio(1); mmas(1); __builtin_amdgcn_s_setprio(0);
    __builtin_amdgcn_s_barrier();
    // ph3: slot0 (F0,k1)
    loadA(0, 0, 1); loadB(0, 1);
    __builtin_amdgcn_s_barrier();
    asm volatile("s_waitcnt lgkmcnt(0)" ::: "memory");
    __builtin_amdgcn_s_setprio(1); mmas(0); __builtin_amdgcn_s_setprio(0);
    __builtin_amdgcn_s_barrier();
    // ph4: slot0 (F1,k1); stage A0,A2 (t0+2 -> slot0; those rows dead since end-ph3)
    // checkpoint: confirm tile t0+1 fully landed (leave only this phase's 2 in flight)
    loadA(0, 1, 1);
    if (st) { stageA(0, t0 + 2, 0); stageA(0, t0 + 2, 2); }
    __builtin_amdgcn_s_barrier();
    asm volatile("s_waitcnt lgkmcnt(0)" ::: "memory");
    __builtin_amdgcn_s_setprio(1); mmas(1); __builtin_amdgcn_s_setprio(0);
    if (st) { asm volatile("s_waitcnt vmcnt(2)" ::: "memory"); }
    else    { asm volatile("s_waitcnt vmcnt(0)" ::: "memory"); }
    __builtin_amdgcn_s_barrier();
    // ph5: slot1 (F0,k0); stage A1,A3,B0 (t0+2; slot0 rows dead since end-ph4)
    loadA(1, 0, 0); loadB(1, 0);
    if (st) { stageA(0, t0 + 2, 1); stageA(0, t0 + 2, 3); stageB(0, t0 + 2, 0); }
    __builtin_amdgcn_s_barrier();
    asm volatile("s_waitcnt lgkmcnt(0)" ::: "memory");
    __builtin_amdgcn_s_setprio(1); mmas(0); __builtin_amdgcn_s_setprio(0);
    __builtin_amdgcn_s_barrier();
    // ph6: slot1 (F1,k0); stage B1-4 (t0+2)
    loadA(1, 1, 0);
    if (st) { stageB(0, t0 + 2, 1); stageB(0, t0 + 2, 2); stageB(0, t0 + 2, 3); stageB(0, t0 + 2, 4); }
    __builtin_amdgcn_s_barrier();
    asm volatile("s_waitcnt lgkmcnt(0)" ::: "memory");
    __builtin_amdgcn_s_setprio(1); mmas(1); __builtin_amdgcn_s_setprio(0);
    __builtin_amdgcn_s_barrier();
    // ph7: slot1 (F0,k1)
    loadA(1, 0, 1); loadB(1, 1);
    __builtin_amdgcn_s_barrier();
    asm volatile("s_waitcnt lgkmcnt(0)" ::: "memory");
    __builtin_amdgcn_s_setprio(1); mmas(0); __builtin_amdgcn_s_setprio(0);
    __builtin_amdgcn_s_barrier();
    // ph8: slot1 (F1,k1); stage A0,A2 (t0+3 -> slot1; F0 rows dead since end-ph7)
    // checkpoint: confirm tile t0+2 fully landed
    loadA(1, 1, 1);
    if (st) { stageA(1, t0 + 3, 0); stageA(1, t0 + 3, 2); }
    __builtin_amdgcn_s_barrier();
    asm volatile("s_waitcnt lgkmcnt(0)" ::: "memory");
    __builtin_amdgcn_s_setprio(1); mmas(1); __builtin_amdgcn_s_setprio(0);
    if (st) { asm volatile("s_waitcnt vmcnt(2)" ::: "memory"); }
    __builtin_amdgcn_s_barrier();
  }

  // epilogue: plain bf16 C write (C/D layout: col = lane&15, row = quad*4 + r)
#pragma unroll
  for (int mf = 0; mf < 8; ++mf)
#pragma unroll
    for (int nf = 0; nf < 5; ++nf) {
      const size_t base = (size_t)(m0 + wm + mf * 16 + quad * 4) * N + (n0 + wn + nf * 16 + f);
#pragma unroll
      for (int r = 0; r < 4; ++r) C[base + (size_t)r * N] = f2bf(acc[mf][nf][r]);
    }
}

// ---------------- fused RMSNorm + RoPE for Q (scale folded in), bf16 in ----------------
__global__ __launch_bounds__(256) void qnorm_rope(const u16* __restrict__ QKV,
                                                  const float* __restrict__ w,
                                                  const float* __restrict__ cosT,
                                                  const float* __restrict__ sinT,
                                                  u16* __restrict__ Qb) {
  const int wv = threadIdx.x >> 6, lane = threadIdx.x & 63;
  const int idx = blockIdx.x * 4 + wv;      // row*16 + h
  const int h = idx & 15, row = idx >> 4;   // row = b*S + s
  const int s = row & (S_LEN - 1), b = row >> 11;
  const u16* base = QKV + (size_t)row * DQKV + h * 256;
  const float v0 = bf2f(base[lane]), v1 = bf2f(base[lane + 64]);
  float ss = v0 * v0 + v1 * v1;
#pragma unroll
  for (int m = 32; m >= 1; m >>= 1) ss += __shfl_xor(ss, m);
  const float rn = rsqrtf(ss * (1.0f / 128.0f) + 1e-6f) * QK_SCALE;
  const float n0 = v0 * rn * (1.0f + w[lane]);
  const float n1 = v1 * rn * (1.0f + w[lane + 64]);
  const float c0 = cosT[(size_t)s * 128 + lane], c1 = cosT[(size_t)s * 128 + lane + 64];
  const float sn0 = sinT[(size_t)s * 128 + lane], sn1 = sinT[(size_t)s * 128 + lane + 64];
  u16* qb = Qb + ((size_t)(b * 16 + h) * S_LEN + s) * 128;
  qb[lane]      = f2bf(n0 * c0 - n1 * sn0);
  qb[lane + 64] = f2bf(n1 * c1 + n0 * sn1);
}

// ---------------- fused RMSNorm + RoPE for K, XOR-swizzled attn layout ----------------
__global__ __launch_bounds__(256) void knorm_rope(const u16* __restrict__ QKV,
                                                  const float* __restrict__ w,
                                                  const float* __restrict__ cosT,
                                                  const float* __restrict__ sinT,
                                                  u16* __restrict__ Kb) {
  const int wv = threadIdx.x >> 6, lane = threadIdx.x & 63;
  const int idx = blockIdx.x * 4 + wv;      // row*4 + g
  const int g = idx & 3, row = idx >> 2;
  const int s = row & (S_LEN - 1), b = row >> 11;
  const u16* base = QKV + (size_t)row * DQKV + DQG + g * 128;
  const float v0 = bf2f(base[lane]), v1 = bf2f(base[lane + 64]);
  float ss = v0 * v0 + v1 * v1;
#pragma unroll
  for (int m = 32; m >= 1; m >>= 1) ss += __shfl_xor(ss, m);
  const float rn = rsqrtf(ss * (1.0f / 128.0f) + 1e-6f);
  const float n0 = v0 * rn * (1.0f + w[lane]);
  const float n1 = v1 * rn * (1.0f + w[lane + 64]);
  const float c0 = cosT[(size_t)s * 128 + lane], c1 = cosT[(size_t)s * 128 + lane + 64];
  const float sn0 = sinT[(size_t)s * 128 + lane], sn1 = sinT[(size_t)s * 128 + lane + 64];
  u16* kb = Kb + ((size_t)(b * 4 + g) * S_LEN + s) * 128;
  const int sw = s & 7;
  const int d0 = lane, d1 = lane + 64;
  const int p0 = (((d0 >> 3) ^ sw) << 3) | (d0 & 7);
  const int p1 = (((d1 >> 3) ^ sw) << 3) | (d1 & 7);
  kb[p0] = f2bf(n0 * c0 - n1 * sn0);
  kb[p1] = f2bf(n1 * c1 + n0 * sn1);
}

// ---------------- V: QKV bf16 cols 4608.. -> Vt bf16 [bg][d][s], attn-swizzled ----------------
__global__ __launch_bounds__(256) void vtrans(const u16* __restrict__ QKV,
                                              u16* __restrict__ Vt) {
  __shared__ u16 tile[32][40];
  const int bg = blockIdx.z;                 // b*4+g
  const int s0 = blockIdx.x * 32, d0 = blockIdx.y * 32;
  const int b = bg >> 2, g = bg & 3;
  const int t = threadIdx.x;
  {
    const int sl = t >> 3, dl4 = (t & 7) * 4;
    const ushort4 v = *reinterpret_cast<const ushort4*>(
        QKV + (size_t)(b * S_LEN + s0 + sl) * DQKV + DQG + 512 + g * 128 + d0 + dl4);
    tile[sl][dl4 + 0] = v.x; tile[sl][dl4 + 1] = v.y;
    tile[sl][dl4 + 2] = v.z; tile[sl][dl4 + 3] = v.w;
  }
  __syncthreads();
  {
    const int dl = t >> 3, sl4 = (t & 7) * 4;
    ushort4 o;
    o.x = tile[sl4 + 0][dl]; o.y = tile[sl4 + 1][dl];
    o.z = tile[sl4 + 2][dl]; o.w = tile[sl4 + 3][dl];
    const int d = d0 + dl, s = s0 + sl4;
    const size_t base = (size_t)(bg * 128 + d) * S_LEN + (s & ~63);
    const int pos = ((((s >> 3) & 7) ^ (d & 7)) << 3) | (s & 7);
    *reinterpret_cast<ushort4*>(Vt + base + pos) = o;
  }
}

// ---------------- MFMA flash attention + gating (no-max softmax, paired causal) ----------------
__global__ __launch_bounds__(256) void attn(const u16* __restrict__ Qb,
                                            const u16* __restrict__ Kb,
                                            const u16* __restrict__ Vt,
                                            const u16* __restrict__ QKV,
                                            u16* __restrict__ ctxg) {
  __shared__ __align__(16) u16 Ks[64 * 128];   // [key][d], chunk-swizzled
  __shared__ __align__(16) u16 Vts[128 * 64];  // [d][key], chunk-swizzled
  __shared__ __align__(16) u16 Ps[4][16 * 68]; // per-wave P [q][key], stride 68
  const int tid = threadIdx.x, wv = tid >> 6, lane = tid & 63;
  const int ip = blockIdx.x, bh = blockIdx.y;
  const int b = bh >> 4, h = bh & 15, g = h >> 2, bg = b * 4 + g;
  const int f = lane & 15, quad = lane >> 4, fq = quad * 8;
  const int fsw = f & 7;
  const u16* Kp = Kb + (size_t)bg * S_LEN * 128;
  const u16* Vp = Vt + (size_t)bg * 128 * S_LEN;
  u16* Pw = Ps[wv];

  for (int pass = 0; pass < 2; ++pass) {
    const int qt = pass ? 31 - ip : ip;
    const u16* Qp = Qb + ((size_t)bh * S_LEN + qt * 64 + wv * 16) * 128;
    bf16x8 aq[4];
#pragma unroll
    for (int c = 0; c < 4; ++c)
      aq[c] = *reinterpret_cast<const bf16x8*>(&Qp[(size_t)f * 128 + c * 32 + fq]);

    floatx4 o[8] = {};
    float lsum[4] = {0.f, 0.f, 0.f, 0.f};
    const int nkt = qt + 1;

    for (int kt = 0; kt < nkt; ++kt) {
      const int k0 = kt * 64;
#pragma unroll
      for (int i = 0; i < 4; ++i) {
        const int j = wv * 4 + i;
        gload_lds16(Kp + (size_t)k0 * 128 + j * 512 + lane * 8, &Ks[j * 512]);
      }
#pragma unroll
      for (int i = 0; i < 4; ++i) {
        const int r0 = (wv * 4 + i) * 8;
        gload_lds16(Vp + (size_t)(r0 + (lane >> 3)) * S_LEN + k0 + (lane & 7) * 8,
                    &Vts[r0 * 64]);
      }
      __syncthreads();

      floatx4 sc[4] = {};
#pragma unroll
      for (int c = 0; c < 4; ++c) {
#pragma unroll
        for (int n = 0; n < 4; ++n) {
          bf16x8 bk = *reinterpret_cast<const bf16x8*>(
              &Ks[(n * 16 + f) * 128 + (((4 * c + quad) ^ fsw) << 3)]);
          sc[n] = __builtin_amdgcn_mfma_f32_16x16x32_bf16(aq[c], bk, sc[n], 0, 0, 0);
        }
      }

      const int qrow0 = qt * 64 + wv * 16 + quad * 4;
#pragma unroll
      for (int n = 0; n < 4; ++n) {
        const int key = k0 + n * 16 + f;
#pragma unroll
        for (int r = 0; r < 4; ++r) {
          const float p = (key <= qrow0 + r) ? __expf(sc[n][r]) : 0.f;
          lsum[r] += p;
          Pw[(quad * 4 + r) * 68 + n * 16 + f] = f2bf(p);
        }
      }

#pragma unroll
      for (int kf = 0; kf < 2; ++kf) {
        bf16x8 pf = *reinterpret_cast<const bf16x8*>(&Pw[f * 68 + kf * 32 + fq]);
#pragma unroll
        for (int dt = 0; dt < 8; ++dt) {
          bf16x8 bv = *reinterpret_cast<const bf16x8*>(
              &Vts[(dt * 16 + f) * 64 + (((4 * kf + quad) ^ fsw) << 3)]);
          o[dt] = __builtin_amdgcn_mfma_f32_16x16x32_bf16(pf, bv, o[dt], 0, 0, 0);
        }
      }
      __syncthreads();
    }

#pragma unroll
    for (int r = 0; r < 4; ++r) {
#pragma unroll
      for (int mm = 8; mm >= 1; mm >>= 1) lsum[r] += __shfl_xor(lsum[r], mm);
    }

    // epilogue: 1/l, sigmoid gate (bf16), swizzled bf16 ctx write
#pragma unroll
    for (int r = 0; r < 4; ++r) {
      const int s = qt * 64 + wv * 16 + quad * 4 + r;
      const size_t grow = (size_t)b * S_LEN + s;
      const float inv = 1.0f / lsum[r];
#pragma unroll
      for (int dt = 0; dt < 8; ++dt) {
        const int d = dt * 16 + f;
        const float gate = bf2f(QKV[grow * DQKV + h * 256 + 128 + d]);
        const float val = o[dt][r] * inv * (1.0f / (1.0f + __expf(-gate)));
        const int col = h * 128 + d;
        ctxg[grow * 2048 + swz(col, (int)grow)] = f2bf(val);
      }
    }
  }
}

extern "C" void kernel_launch(void* const* d_in, const int* in_sizes, int n_in,
                              void* d_out, int out_size, void* d_ws, size_t ws_size,
                              hipStream_t stream) {
  const float* x    = (const float*)d_in[0];
  const float* Wq   = (const float*)d_in[1];
  const float* Wk   = (const float*)d_in[2];
  const float* Wv   = (const float*)d_in[3];
  const float* Wo   = (const float*)d_in[4];
  const float* qnw  = (const float*)d_in[5];
  const float* knw  = (const float*)d_in[6];
  const float* cosT = (const float*)d_in[7];
  const float* sinT = (const float*)d_in[8];
  // d_in[9] = mask (unused; causality computed analytically)

  char* p = (char*)d_ws;
  u16*   xb    = (u16*)p;  p += (size_t)NROWS * DIN * 2;       // x bf16 (swizzled)
  u16*   WqkvT = (u16*)p;  p += (size_t)DQKV * DIN * 2;        // [Wq|Wk|Wv]^T (swizzled)
  u16*   WoT   = (u16*)p;  p += (size_t)2048 * 2048 * 2;       // Wo^T (swizzled)
  u16*   QKVb  = (u16*)p;  p += (size_t)NROWS * DQKV * 2;      // qkv proj bf16 (plain)
  u16*   Qbf   = (u16*)p;  p += (size_t)2 * 16 * S_LEN * 128 * 2;
  u16*   Kbf   = (u16*)p;  p += (size_t)2 * 4 * S_LEN * 128 * 2;
  u16*   Vtb   = (u16*)p;  p += (size_t)2 * 4 * S_LEN * 128 * 2;
  u16*   ctxg  = (u16*)p;  p += (size_t)NROWS * 2048 * 2;      // gated ctx (swizzled)

  cvt_x<<<8192, 256, 0, stream>>>(x, xb);
  tcvt<<<dim3(128, 64), 256, 0, stream>>>(Wq, WqkvT, 2048, 4096, 2048);
  tcvt<<<dim3(16, 64), 256, 0, stream>>>(Wk, WqkvT + (size_t)4096 * 2048, 2048, 512, 2048);
  tcvt<<<dim3(16, 64), 256, 0, stream>>>(Wv, WqkvT + (size_t)4608 * 2048, 2048, 512, 2048);
  tcvt<<<dim3(64, 64), 256, 0, stream>>>(Wo, WoT, 2048, 2048, 2048);

  // QKV projection: 8-phase 256x320 pipeline, grid = 16x16 = 256 WGs (1/CU, no tail)
  gemm_qkv<<<dim3(16, 16), 512, 0, stream>>>(xb, WqkvT, QKVb, NROWS, DQKV, DIN);

  qnorm_rope<<<16384, 256, 0, stream>>>(QKVb, qnw, cosT, sinT, Qbf);
  knorm_rope<<<4096, 256, 0, stream>>>(QKVb, knw, cosT, sinT, Kbf);
  vtrans<<<dim3(64, 4, 8), 256, 0, stream>>>(QKVb, Vtb);

  attn<<<dim3(16, 32), 256, 0, stream>>>(Qbf, Kbf, Vtb, QKVb, ctxg);

  gemm_bt<false><<<dim3(16, 32), 256, 0, stream>>>(ctxg, WoT, (float*)d_out, NROWS, 2048, 2048);
}

// Round 2
// 411.006 us; speedup vs baseline: 1.4101x; 1.4101x over previous
//
#include <hip/hip_runtime.h>

// Problem constants (B=2, S=2048, D_IN=2048, H=16, G=4, HD=128)
#define S_LEN 2048
#define NROWS 4096      // B*S
#define DIN   2048
#define DQKV  5120      // 4096 (q|gate) + 512 K + 512 V
#define DQG   4096

typedef __bf16 bf16x8 __attribute__((ext_vector_type(8)));
typedef float  floatx4 __attribute__((ext_vector_type(4)));
typedef unsigned short u16;

#define QK_SCALE 0.08838834764831845f   // 128^-0.5, folded into Q

__device__ __forceinline__ u16 f2bf(float f) {
  unsigned int u = __float_as_uint(f);
  u += 0x7fffu + ((u >> 16) & 1u);   // RNE
  return (u16)(u >> 16);
}
__device__ __forceinline__ float bf2f(u16 v) {
  return __uint_as_float(((unsigned int)v) << 16);
}
// XOR-8 chunk swizzle within each 64-element column group, keyed by row&7.
__device__ __forceinline__ int swz(int col, int row) {
  return (col & ~63) | ((((col >> 3) & 7) ^ (row & 7)) << 3) | (col & 7);
}

__device__ __forceinline__ void gload_lds16(const void* g, void* l) {
  __builtin_amdgcn_global_load_lds(
      (__attribute__((address_space(1))) void*)(void*)(g),
      (__attribute__((address_space(3))) void*)(l), 16, 0, 0);
}

// ---------------- x fp32 -> bf16, swizzled (C = 2048) ----------------
__global__ __launch_bounds__(256) void cvt_x(const float* __restrict__ src,
                                             u16* __restrict__ dst) {
  const int i = blockIdx.x * 256 + threadIdx.x;   // one float4 per thread
  const int row = i >> 9, col = (i & 511) << 2;   // 512 float4 per row
  const float4 v = reinterpret_cast<const float4*>(src)[i];
  ushort4 o;
  o.x = f2bf(v.x); o.y = f2bf(v.y); o.z = f2bf(v.z); o.w = f2bf(v.w);
  *reinterpret_cast<ushort4*>(dst + (size_t)row * DIN + swz(col, row)) = o;
}

// ---------------- transpose + convert + swizzle: src[R][C] f32 -> dst[C][R] bf16 ----------------
__global__ __launch_bounds__(256) void tcvt(const float* __restrict__ src,
                                            u16* __restrict__ dst,
                                            int R, int C, int dld) {
  __shared__ float tile[32][33];
  const int c0 = blockIdx.x * 32, r0 = blockIdx.y * 32;
  const int t = threadIdx.x;
  {
    const int rl = t >> 3, cl4 = (t & 7) * 4;
    const float4 v = *reinterpret_cast<const float4*>(src + (size_t)(r0 + rl) * C + c0 + cl4);
    tile[rl][cl4 + 0] = v.x; tile[rl][cl4 + 1] = v.y;
    tile[rl][cl4 + 2] = v.z; tile[rl][cl4 + 3] = v.w;
  }
  __syncthreads();
  {
    const int cl = t >> 3, rl4 = (t & 7) * 4;
    ushort4 o;
    o.x = f2bf(tile[rl4 + 0][cl]); o.y = f2bf(tile[rl4 + 1][cl]);
    o.z = f2bf(tile[rl4 + 2][cl]); o.w = f2bf(tile[rl4 + 3][cl]);
    const int rd = c0 + cl, cd = r0 + rl4;      // dst (row, col)
    *reinterpret_cast<ushort4*>(dst + (size_t)rd * dld + swz(cd, rd)) = o;
  }
}

// ---------------- bf16 GEMM, BK=64: C[M][N] = A[M][K] @ Bt[N][K]^T ----------------
// A, Bt stored with swz() layout. C plain (fp32 or bf16).  (kept for the Wo GEMM)
template <bool BF16_OUT>
__global__ __launch_bounds__(256) void gemm_bt(const u16* __restrict__ A,
                                               const u16* __restrict__ Bt,
                                               void* __restrict__ Cv,
                                               int M, int N, int K) {
  __shared__ __align__(16) u16 As[128 * 64];
  __shared__ __align__(16) u16 Bs[128 * 64];
  const int tid = threadIdx.x, wv = tid >> 6, lane = tid & 63;
  const int m0 = blockIdx.y * 128, n0 = blockIdx.x * 128;
  const int wm = (wv >> 1) * 64, wn = (wv & 1) * 64;
  const int frow = lane & 15, quad = lane >> 4, fsw = frow & 7;
  const int srow = lane >> 3, scol = (lane & 7) * 8;
  floatx4 acc[4][4] = {};
  for (int k0 = 0; k0 < K; k0 += 64) {
#pragma unroll
    for (int i = 0; i < 4; ++i) {
      const int rr = (wv * 4 + i) * 8;
      gload_lds16(A  + (size_t)(m0 + rr + srow) * K + k0 + scol, &As[rr * 64]);
      gload_lds16(Bt + (size_t)(n0 + rr + srow) * K + k0 + scol, &Bs[rr * 64]);
    }
    __syncthreads();
#pragma unroll
    for (int ks = 0; ks < 2; ++ks) {
      bf16x8 af[4], bfr[4];
#pragma unroll
      for (int mi = 0; mi < 4; ++mi)
        af[mi] = *reinterpret_cast<const bf16x8*>(
            &As[(wm + mi * 16 + frow) * 64 + (((ks * 4 + quad) ^ fsw) << 3)]);
#pragma unroll
      for (int ni = 0; ni < 4; ++ni)
        bfr[ni] = *reinterpret_cast<const bf16x8*>(
            &Bs[(wn + ni * 16 + frow) * 64 + (((ks * 4 + quad) ^ fsw) << 3)]);
#pragma unroll
      for (int mi = 0; mi < 4; ++mi)
#pragma unroll
        for (int ni = 0; ni < 4; ++ni)
          acc[mi][ni] = __builtin_amdgcn_mfma_f32_16x16x32_bf16(af[mi], bfr[ni], acc[mi][ni], 0, 0, 0);
    }
    __syncthreads();
  }
  const int crow = (lane >> 4) * 4, ccol = lane & 15;
#pragma unroll
  for (int mi = 0; mi < 4; ++mi)
#pragma unroll
    for (int ni = 0; ni < 4; ++ni) {
      const size_t base = (size_t)(m0 + wm + mi * 16 + crow) * N + (n0 + wn + ni * 16 + ccol);
      if constexpr (BF16_OUT) {
        u16* C = (u16*)Cv;
#pragma unroll
        for (int r = 0; r < 4; ++r) C[base + (size_t)r * N] = f2bf(acc[mi][ni][r]);
      } else {
        float* C = (float*)Cv;
#pragma unroll
        for (int r = 0; r < 4; ++r) C[base + (size_t)r * N] = acc[mi][ni][r];
      }
    }
}

// ---------------- 8-phase deep-pipelined bf16 GEMM, 128x320 tile, BK=64 ----------------
// C[M][N] = A[M][K] @ Bt[N][K]^T ; A,Bt swz()-swizzled; C plain bf16.
// 512 threads = 8 waves (2M x 4N). Wave tile 64x80 -> acc[4][5] = 80 regs (the
// round-1 spill fix: 128x80 wave tile needed 160 acc regs > the 256-reg budget
// of a 512-thread block and spilled 275 MB/dispatch to scratch).
// M split per wave: rows wm..wm+31 (F0, in stage-unit A0) and wm+64..wm+95 (F1,
// unit A1), wm=(wv>>2)*32 -> stage units align exactly with F-half deadness.
// LDS: 2 slots x (A 128x64 + B 320x64) = 112 KiB -> 1 WG/CU.
// Stage unit = 64 rows x 64 k = 8 KiB = 1 global_load_lds_dwordx4/thread.
// 7 units/tile (A0,A1,B0..B4). Placement (deadness-checked):
//   slot1 tile: ph8prev{A0,B0} ph1{A1,B1,B2} ph2{B3,B4}; slot0' tile:
//   ph4{A0,B0} ph5{A1,B1,B2} ph6{B3,B4}. Counted vmcnt(2) at ph4/ph8 only.
__global__ __launch_bounds__(512, 2) void gemm_qkv(const u16* __restrict__ A,
                                                   const u16* __restrict__ Bt,
                                                   u16* __restrict__ C,
                                                   int M, int N, int K) {
  __shared__ __align__(16) u16 As[2][128 * 64];   // 32 KiB
  __shared__ __align__(16) u16 Bs[2][320 * 64];   // 80 KiB
  const int tid = threadIdx.x, wv = tid >> 6, lane = tid & 63;
  // XCD-bijective swizzle (grid = 512 WGs, multiple of 8)
  const int nx = gridDim.x;
  const int orig = blockIdx.y * nx + blockIdx.x;
  const int cpx = (nx * gridDim.y) >> 3;
  const int wgid = (orig & 7) * cpx + (orig >> 3);
  const int m0 = (wgid / nx) * 128, n0 = (wgid % nx) * 320;
  const int wm = (wv >> 2) * 32, wn = (wv & 3) * 80;
  const int f = lane & 15, quad = lane >> 4, fs = f & 7;

  const u16* Ab = A  + (size_t)(m0 + wv * 8 + (lane >> 3)) * K + (lane & 7) * 8;
  const u16* Bb = Bt + (size_t)(n0 + wv * 8 + (lane >> 3)) * K + (lane & 7) * 8;

  floatx4 acc[4][5] = {};
  bf16x8 af[2], bfr[5];

  auto stageA = [&](int sl, int t, int u) {
    gload_lds16(Ab + (size_t)u * 64 * K + (size_t)t * 64, &As[sl][(u * 64 + wv * 8) * 64]);
  };
  auto stageB = [&](int sl, int t, int u) {
    gload_lds16(Bb + (size_t)u * 64 * K + (size_t)t * 64, &Bs[sl][(u * 64 + wv * 8) * 64]);
  };
  auto loadA = [&](int sl, int fh, int ks) {
#pragma unroll
    for (int mf = 0; mf < 2; ++mf)
      af[mf] = *reinterpret_cast<const bf16x8*>(
          &As[sl][(fh * 64 + wm + mf * 16 + f) * 64 + ((((ks << 2) + quad) ^ fs) << 3)]);
  };
  auto loadB = [&](int sl, int ks) {
#pragma unroll
    for (int nf = 0; nf < 5; ++nf)
      bfr[nf] = *reinterpret_cast<const bf16x8*>(
          &Bs[sl][(wn + nf * 16 + f) * 64 + ((((ks << 2) + quad) ^ fs) << 3)]);
  };
  auto mmas = [&](int fh) {
#pragma unroll
    for (int mf = 0; mf < 2; ++mf)
#pragma unroll
      for (int nf = 0; nf < 5; ++nf)
        acc[fh * 2 + mf][nf] = __builtin_amdgcn_mfma_f32_16x16x32_bf16(
            af[mf], bfr[nf], acc[fh * 2 + mf][nf], 0, 0, 0);
  };

  // prologue: tile0 -> slot0 (7 units), then tile1 {A0,B0} -> slot1 (stay in flight)
  stageA(0, 0, 0); stageA(0, 0, 1);
#pragma unroll
  for (int u = 0; u < 5; ++u) stageB(0, 0, u);
  stageA(1, 1, 0); stageB(1, 1, 0);
  asm volatile("s_waitcnt vmcnt(2)" ::: "memory");
  __builtin_amdgcn_s_barrier();

  const int IT = K >> 7;   // 2 K-tiles per iteration
#pragma unroll 1
  for (int i = 0; i < IT; ++i) {
    const int t0 = 2 * i;
    const bool st = (i < IT - 1);
    // ph1: slot0 (F0,k0); stage slot1 tile: A1 (s1-F1 dead since end-ph8), B1,B2
    loadA(0, 0, 0); loadB(0, 0);
    stageA(1, t0 + 1, 1); stageB(1, t0 + 1, 1); stageB(1, t0 + 1, 2);
    __builtin_amdgcn_s_barrier();
    asm volatile("s_waitcnt lgkmcnt(0)" ::: "memory");
    __builtin_amdgcn_s_setprio(1); mmas(0); __builtin_amdgcn_s_setprio(0);
    __builtin_amdgcn_s_barrier();
    // ph2: slot0 (F1,k0); B(k0) frags reused; stage slot1: B3,B4
    loadA(0, 1, 0);
    stageB(1, t0 + 1, 3); stageB(1, t0 + 1, 4);
    __builtin_amdgcn_s_barrier();
    asm volatile("s_waitcnt lgkmcnt(0)" ::: "memory");
    __builtin_amdgcn_s_setprio(1); mmas(1); __builtin_amdgcn_s_setprio(0);
    __builtin_amdgcn_s_barrier();
    // ph3: slot0 (F0,k1)   [last reads of s0: A-F0 rows + all B rows]
    loadA(0, 0, 1); loadB(0, 1);
    __builtin_amdgcn_s_barrier();
    asm volatile("s_waitcnt lgkmcnt(0)" ::: "memory");
    __builtin_amdgcn_s_setprio(1); mmas(0); __builtin_amdgcn_s_setprio(0);
    __builtin_amdgcn_s_barrier();
    // ph4: slot0 (F1,k1); stage slot0' (t0+2): A0,B0 (dead since end-ph3)
    // checkpoint: slot1 tile fully landed (last issued ph2, 2 phases old)
    loadA(0, 1, 1);
    if (st) { stageA(0, t0 + 2, 0); stageB(0, t0 + 2, 0); }
    __builtin_amdgcn_s_barrier();
    asm volatile("s_waitcnt lgkmcnt(0)" ::: "memory");
    __builtin_amdgcn_s_setprio(1); mmas(1); __builtin_amdgcn_s_setprio(0);
    if (st) { asm volatile("s_waitcnt vmcnt(2)" ::: "memory"); }
    else    { asm volatile("s_waitcnt vmcnt(0)" ::: "memory"); }
    __builtin_amdgcn_s_barrier();
    // ph5: slot1 (F0,k0); stage slot0': A1 (s0-F1 dead since end-ph4), B1,B2
    loadA(1, 0, 0); loadB(1, 0);
    if (st) { stageA(0, t0 + 2, 1); stageB(0, t0 + 2, 1); stageB(0, t0 + 2, 2); }
    __builtin_amdgcn_s_barrier();
    asm volatile("s_waitcnt lgkmcnt(0)" ::: "memory");
    __builtin_amdgcn_s_setprio(1); mmas(0); __builtin_amdgcn_s_setprio(0);
    __builtin_amdgcn_s_barrier();
    // ph6: slot1 (F1,k0); stage slot0': B3,B4
    loadA(1, 1, 0);
    if (st) { stageB(0, t0 + 2, 3); stageB(0, t0 + 2, 4); }
    __builtin_amdgcn_s_barrier();
    asm volatile("s_waitcnt lgkmcnt(0)" ::: "memory");
    __builtin_amdgcn_s_setprio(1); mmas(1); __builtin_amdgcn_s_setprio(0);
    __builtin_amdgcn_s_barrier();
    // ph7: slot1 (F0,k1)   [last reads of s1: A-F0 rows + all B rows]
    loadA(1, 0, 1); loadB(1, 1);
    __builtin_amdgcn_s_barrier();
    asm volatile("s_waitcnt lgkmcnt(0)" ::: "memory");
    __builtin_amdgcn_s_setprio(1); mmas(0); __builtin_amdgcn_s_setprio(0);
    __builtin_amdgcn_s_barrier();
    // ph8: slot1 (F1,k1); stage slot1'' (t0+3): A0,B0 (dead since end-ph7)
    // checkpoint: slot0' tile fully landed (last issued ph6, 2 phases old)
    loadA(1, 1, 1);
    if (st) { stageA(1, t0 + 3, 0); stageB(1, t0 + 3, 0); }
    __builtin_amdgcn_s_barrier();
    asm volatile("s_waitcnt lgkmcnt(0)" ::: "memory");
    __builtin_amdgcn_s_setprio(1); mmas(1); __builtin_amdgcn_s_setprio(0);
    if (st) { asm volatile("s_waitcnt vmcnt(2)" ::: "memory"); }
    __builtin_amdgcn_s_barrier();
  }

  // epilogue: plain bf16 C write (C/D layout: col = lane&15, row = quad*4 + r)
#pragma unroll
  for (int mf = 0; mf < 4; ++mf)
#pragma unroll
    for (int nf = 0; nf < 5; ++nf) {
      const size_t base = (size_t)(m0 + (mf >> 1) * 64 + wm + (mf & 1) * 16 + quad * 4) * N
                        + (n0 + wn + nf * 16 + f);
#pragma unroll
      for (int r = 0; r < 4; ++r) C[base + (size_t)r * N] = f2bf(acc[mf][nf][r]);
    }
}

// ---------------- fused RMSNorm + RoPE for Q (scale folded in), bf16 in ----------------
__global__ __launch_bounds__(256) void qnorm_rope(const u16* __restrict__ QKV,
                                                  const float* __restrict__ w,
                                                  const float* __restrict__ cosT,
                                                  const float* __restrict__ sinT,
                                                  u16* __restrict__ Qb) {
  const int wv = threadIdx.x >> 6, lane = threadIdx.x & 63;
  const int idx = blockIdx.x * 4 + wv;      // row*16 + h
  const int h = idx & 15, row = idx >> 4;   // row = b*S + s
  const int s = row & (S_LEN - 1), b = row >> 11;
  const u16* base = QKV + (size_t)row * DQKV + h * 256;
  const float v0 = bf2f(base[lane]), v1 = bf2f(base[lane + 64]);
  float ss = v0 * v0 + v1 * v1;
#pragma unroll
  for (int m = 32; m >= 1; m >>= 1) ss += __shfl_xor(ss, m);
  const float rn = rsqrtf(ss * (1.0f / 128.0f) + 1e-6f) * QK_SCALE;
  const float n0 = v0 * rn * (1.0f + w[lane]);
  const float n1 = v1 * rn * (1.0f + w[lane + 64]);
  const float c0 = cosT[(size_t)s * 128 + lane], c1 = cosT[(size_t)s * 128 + lane + 64];
  const float sn0 = sinT[(size_t)s * 128 + lane], sn1 = sinT[(size_t)s * 128 + lane + 64];
  u16* qb = Qb + ((size_t)(b * 16 + h) * S_LEN + s) * 128;
  qb[lane]      = f2bf(n0 * c0 - n1 * sn0);
  qb[lane + 64] = f2bf(n1 * c1 + n0 * sn1);
}

// ---------------- fused RMSNorm + RoPE for K, XOR-swizzled attn layout ----------------
__global__ __launch_bounds__(256) void knorm_rope(const u16* __restrict__ QKV,
                                                  const float* __restrict__ w,
                                                  const float* __restrict__ cosT,
                                                  const float* __restrict__ sinT,
                                                  u16* __restrict__ Kb) {
  const int wv = threadIdx.x >> 6, lane = threadIdx.x & 63;
  const int idx = blockIdx.x * 4 + wv;      // row*4 + g
  const int g = idx & 3, row = idx >> 2;
  const int s = row & (S_LEN - 1), b = row >> 11;
  const u16* base = QKV + (size_t)row * DQKV + DQG + g * 128;
  const float v0 = bf2f(base[lane]), v1 = bf2f(base[lane + 64]);
  float ss = v0 * v0 + v1 * v1;
#pragma unroll
  for (int m = 32; m >= 1; m >>= 1) ss += __shfl_xor(ss, m);
  const float rn = rsqrtf(ss * (1.0f / 128.0f) + 1e-6f);
  const float n0 = v0 * rn * (1.0f + w[lane]);
  const float n1 = v1 * rn * (1.0f + w[lane + 64]);
  const float c0 = cosT[(size_t)s * 128 + lane], c1 = cosT[(size_t)s * 128 + lane + 64];
  const float sn0 = sinT[(size_t)s * 128 + lane], sn1 = sinT[(size_t)s * 128 + lane + 64];
  u16* kb = Kb + ((size_t)(b * 4 + g) * S_LEN + s) * 128;
  const int sw = s & 7;
  const int d0 = lane, d1 = lane + 64;
  const int p0 = (((d0 >> 3) ^ sw) << 3) | (d0 & 7);
  const int p1 = (((d1 >> 3) ^ sw) << 3) | (d1 & 7);
  kb[p0] = f2bf(n0 * c0 - n1 * sn0);
  kb[p1] = f2bf(n1 * c1 + n0 * sn1);
}

// ---------------- V: QKV bf16 cols 4608.. -> Vt bf16 [bg][d][s], attn-swizzled ----------------
__global__ __launch_bounds__(256) void vtrans(const u16* __restrict__ QKV,
                                              u16* __restrict__ Vt) {
  __shared__ u16 tile[32][40];
  const int bg = blockIdx.z;                 // b*4+g
  const int s0 = blockIdx.x * 32, d0 = blockIdx.y * 32;
  const int b = bg >> 2, g = bg & 3;
  const int t = threadIdx.x;
  {
    const int sl = t >> 3, dl4 = (t & 7) * 4;
    const ushort4 v = *reinterpret_cast<const ushort4*>(
        QKV + (size_t)(b * S_LEN + s0 + sl) * DQKV + DQG + 512 + g * 128 + d0 + dl4);
    tile[sl][dl4 + 0] = v.x; tile[sl][dl4 + 1] = v.y;
    tile[sl][dl4 + 2] = v.z; tile[sl][dl4 + 3] = v.w;
  }
  __syncthreads();
  {
    const int dl = t >> 3, sl4 = (t & 7) * 4;
    ushort4 o;
    o.x = tile[sl4 + 0][dl]; o.y = tile[sl4 + 1][dl];
    o.z = tile[sl4 + 2][dl]; o.w = tile[sl4 + 3][dl];
    const int d = d0 + dl, s = s0 + sl4;
    const size_t base = (size_t)(bg * 128 + d) * S_LEN + (s & ~63);
    const int pos = ((((s >> 3) & 7) ^ (d & 7)) << 3) | (s & 7);
    *reinterpret_cast<ushort4*>(Vt + base + pos) = o;
  }
}

// ---------------- MFMA flash attention + gating (no-max softmax, paired causal) ----------------
__global__ __launch_bounds__(256) void attn(const u16* __restrict__ Qb,
                                            const u16* __restrict__ Kb,
                                            const u16* __restrict__ Vt,
                                            const u16* __restrict__ QKV,
                                            u16* __restrict__ ctxg) {
  __shared__ __align__(16) u16 Ks[64 * 128];   // [key][d], chunk-swizzled
  __shared__ __align__(16) u16 Vts[128 * 64];  // [d][key], chunk-swizzled
  __shared__ __align__(16) u16 Ps[4][16 * 68]; // per-wave P [q][key], stride 68
  const int tid = threadIdx.x, wv = tid >> 6, lane = tid & 63;
  const int ip = blockIdx.x, bh = blockIdx.y;
  const int b = bh >> 4, h = bh & 15, g = h >> 2, bg = b * 4 + g;
  const int f = lane & 15, quad = lane >> 4, fq = quad * 8;
  const int fsw = f & 7;
  const u16* Kp = Kb + (size_t)bg * S_LEN * 128;
  const u16* Vp = Vt + (size_t)bg * 128 * S_LEN;
  u16* Pw = Ps[wv];

  for (int pass = 0; pass < 2; ++pass) {
    const int qt = pass ? 31 - ip : ip;
    const u16* Qp = Qb + ((size_t)bh * S_LEN + qt * 64 + wv * 16) * 128;
    bf16x8 aq[4];
#pragma unroll
    for (int c = 0; c < 4; ++c)
      aq[c] = *reinterpret_cast<const bf16x8*>(&Qp[(size_t)f * 128 + c * 32 + fq]);

    floatx4 o[8] = {};
    float lsum[4] = {0.f, 0.f, 0.f, 0.f};
    const int nkt = qt + 1;

    for (int kt = 0; kt < nkt; ++kt) {
      const int k0 = kt * 64;
#pragma unroll
      for (int i = 0; i < 4; ++i) {
        const int j = wv * 4 + i;
        gload_lds16(Kp + (size_t)k0 * 128 + j * 512 + lane * 8, &Ks[j * 512]);
      }
#pragma unroll
      for (int i = 0; i < 4; ++i) {
        const int r0 = (wv * 4 + i) * 8;
        gload_lds16(Vp + (size_t)(r0 + (lane >> 3)) * S_LEN + k0 + (lane & 7) * 8,
                    &Vts[r0 * 64]);
      }
      __syncthreads();

      floatx4 sc[4] = {};
#pragma unroll
      for (int c = 0; c < 4; ++c) {
#pragma unroll
        for (int n = 0; n < 4; ++n) {
          bf16x8 bk = *reinterpret_cast<const bf16x8*>(
              &Ks[(n * 16 + f) * 128 + (((4 * c + quad) ^ fsw) << 3)]);
          sc[n] = __builtin_amdgcn_mfma_f32_16x16x32_bf16(aq[c], bk, sc[n], 0, 0, 0);
        }
      }

      const int qrow0 = qt * 64 + wv * 16 + quad * 4;
#pragma unroll
      for (int n = 0; n < 4; ++n) {
        const int key = k0 + n * 16 + f;
#pragma unroll
        for (int r = 0; r < 4; ++r) {
          const float p = (key <= qrow0 + r) ? __expf(sc[n][r]) : 0.f;
          lsum[r] += p;
          Pw[(quad * 4 + r) * 68 + n * 16 + f] = f2bf(p);
        }
      }

#pragma unroll
      for (int kf = 0; kf < 2; ++kf) {
        bf16x8 pf = *reinterpret_cast<const bf16x8*>(&Pw[f * 68 + kf * 32 + fq]);
#pragma unroll
        for (int dt = 0; dt < 8; ++dt) {
          bf16x8 bv = *reinterpret_cast<const bf16x8*>(
              &Vts[(dt * 16 + f) * 64 + (((4 * kf + quad) ^ fsw) << 3)]);
          o[dt] = __builtin_amdgcn_mfma_f32_16x16x32_bf16(pf, bv, o[dt], 0, 0, 0);
        }
      }
      __syncthreads();
    }

#pragma unroll
    for (int r = 0; r < 4; ++r) {
#pragma unroll
      for (int mm = 8; mm >= 1; mm >>= 1) lsum[r] += __shfl_xor(lsum[r], mm);
    }

    // epilogue: 1/l, sigmoid gate (bf16), swizzled bf16 ctx write
#pragma unroll
    for (int r = 0; r < 4; ++r) {
      const int s = qt * 64 + wv * 16 + quad * 4 + r;
      const size_t grow = (size_t)b * S_LEN + s;
      const float inv = 1.0f / lsum[r];
#pragma unroll
      for (int dt = 0; dt < 8; ++dt) {
        const int d = dt * 16 + f;
        const float gate = bf2f(QKV[grow * DQKV + h * 256 + 128 + d]);
        const float val = o[dt][r] * inv * (1.0f / (1.0f + __expf(-gate)));
        const int col = h * 128 + d;
        ctxg[grow * 2048 + swz(col, (int)grow)] = f2bf(val);
      }
    }
  }
}

extern "C" void kernel_launch(void* const* d_in, const int* in_sizes, int n_in,
                              void* d_out, int out_size, void* d_ws, size_t ws_size,
                              hipStream_t stream) {
  const float* x    = (const float*)d_in[0];
  const float* Wq   = (const float*)d_in[1];
  const float* Wk   = (const float*)d_in[2];
  const float* Wv   = (const float*)d_in[3];
  const float* Wo   = (const float*)d_in[4];
  const float* qnw  = (const float*)d_in[5];
  const float* knw  = (const float*)d_in[6];
  const float* cosT = (const float*)d_in[7];
  const float* sinT = (const float*)d_in[8];
  // d_in[9] = mask (unused; causality computed analytically)

  char* p = (char*)d_ws;
  u16*   xb    = (u16*)p;  p += (size_t)NROWS * DIN * 2;       // x bf16 (swizzled)
  u16*   WqkvT = (u16*)p;  p += (size_t)DQKV * DIN * 2;        // [Wq|Wk|Wv]^T (swizzled)
  u16*   WoT   = (u16*)p;  p += (size_t)2048 * 2048 * 2;       // Wo^T (swizzled)
  u16*   QKVb  = (u16*)p;  p += (size_t)NROWS * DQKV * 2;      // qkv proj bf16 (plain)
  u16*   Qbf   = (u16*)p;  p += (size_t)2 * 16 * S_LEN * 128 * 2;
  u16*   Kbf   = (u16*)p;  p += (size_t)2 * 4 * S_LEN * 128 * 2;
  u16*   Vtb   = (u16*)p;  p += (size_t)2 * 4 * S_LEN * 128 * 2;
  u16*   ctxg  = (u16*)p;  p += (size_t)NROWS * 2048 * 2;      // gated ctx (swizzled)

  cvt_x<<<8192, 256, 0, stream>>>(x, xb);
  tcvt<<<dim3(128, 64), 256, 0, stream>>>(Wq, WqkvT, 2048, 4096, 2048);
  tcvt<<<dim3(16, 64), 256, 0, stream>>>(Wk, WqkvT + (size_t)4096 * 2048, 2048, 512, 2048);
  tcvt<<<dim3(16, 64), 256, 0, stream>>>(Wv, WqkvT + (size_t)4608 * 2048, 2048, 512, 2048);
  tcvt<<<dim3(64, 64), 256, 0, stream>>>(Wo, WoT, 2048, 2048, 2048);

  // QKV projection: 8-phase 128x320 pipeline, grid = 16x32 = 512 WGs (2/CU, no tail)
  gemm_qkv<<<dim3(16, 32), 512, 0, stream>>>(xb, WqkvT, QKVb, NROWS, DQKV, DIN);

  qnorm_rope<<<16384, 256, 0, stream>>>(QKVb, qnw, cosT, sinT, Qbf);
  knorm_rope<<<4096, 256, 0, stream>>>(QKVb, knw, cosT, sinT, Kbf);
  vtrans<<<dim3(64, 4, 8), 256, 0, stream>>>(QKVb, Vtb);

  attn<<<dim3(16, 32), 256, 0, stream>>>(Qbf, Kbf, Vtb, QKVb, ctxg);

  gemm_bt<false><<<dim3(16, 32), 256, 0, stream>>>(ctxg, WoT, (float*)d_out, NROWS, 2048, 2048);
}